// Round 2
// baseline (498.949 us; speedup 1.0000x reference)
//
#include <hip/hip_runtime.h>
#include <hip/hip_bf16.h>

// SiglipSdpaAttention: B=32, N=1024, D=1152, R=4, M=N/R=256.
// Algebra: merge commutes with projections; softmax drops row-constant terms.
//   S = Q@Km^T: expand -> x·(Wq^T Wk)·x_m^T + c[m],  c = x_m·(Wk^T bq)
//   out = P·Vm·Wo^T + bo = P·(x_m·(Wo Wv)^T + Wo bv) + bo
//   [U | VW] = x_m @ [Wqk ; Wvo]^T + [0 | Wo·bv],  Wqk=Wq^T·Wk, Wvo=Wo·Wv
//   P = softmax((x@U^T + c[m]) / sqrt(D));  out = P@VW + bo
// Total ~88 GFLOP. GEMMs bf16 MFMA 16x16x32, 128x128 tile, global_load_lds
// width-16 staging, XCD swizzle.
// R2: counted-vmcnt rotating pipeline (T3+T4): raw s_barrier + inline-asm
//     s_waitcnt vmcnt(N) that never drains to 0 in the main loop. gemm_bt:
//     3 LDS buffers, stage t+2 before compute t, steady vmcnt(4).
//     scores: 4 buffers, steady vmcnt(6) (2 waves/SIMD -> needs deep ILP).

typedef __bf16 bf16;
typedef __attribute__((ext_vector_type(8))) __bf16 bf16x8;
typedef __attribute__((ext_vector_type(4))) __bf16 bf16x4;
typedef __attribute__((ext_vector_type(4))) float f32x4;

#define GAS __attribute__((address_space(1)))
#define LAS __attribute__((address_space(3)))

#define WAITVM(N) asm volatile("s_waitcnt vmcnt(" #N ")" ::: "memory")
#define WAITLGKM0 asm volatile("s_waitcnt lgkmcnt(0)" ::: "memory")
#define BAR() __builtin_amdgcn_s_barrier()

__device__ __forceinline__ void async_copy16(const void* g, void* s) {
    __builtin_amdgcn_global_load_lds((GAS unsigned int*)g, (LAS unsigned int*)s, 16, 0, 0);
}

// C = A * B^T (+bias) * scale. A:[M x K] rowmajor (lda), B:[N x K] rowmajor (ldb),
// C:[M x N] (ldc). Tile 128x128, BK=32, 256 thr = 4 waves (2x2 of 64x64).
// 3-deep counted-vmcnt pipeline: one raw barrier per K-iter, loads never drained
// to 0 in steady state (4 loads/wave/tile in flight across 2 compute phases).
template <typename OutT, bool HAS_BIAS>
__global__ __launch_bounds__(256) void gemm_bt(
    const bf16* __restrict__ A, const bf16* __restrict__ B,
    const float* __restrict__ bias, OutT* __restrict__ C,
    int N, int K, int lda, int ldb, int ldc, float scale,
    long sAb, long sBb, long sCb) {
    __shared__ __align__(16) bf16 As[3][128 * 32];
    __shared__ __align__(16) bf16 Bs[3][128 * 32];
    const int tid  = threadIdx.x;
    const int wave = tid >> 6;
    const int lane = tid & 63;
    const int quad = lane >> 4;
    const int l16  = lane & 15;
    const int wM   = (wave >> 1) * 64;
    const int wN   = (wave & 1) * 64;

    // XCD swizzle: all x-tiles of an A-panel on one XCD (A fetched once/panel).
    int bx = blockIdx.x, by = blockIdx.y;
    const int nbx = gridDim.x, nby = gridDim.y;
    if (((nby & 7) == 0) && (nbx % 9 == 0)) {
        int lid = by * nbx + bx;
        int xcd = lid & 7;
        int s   = lid >> 3;
        int Pn  = nby >> 3;
        int gsz = 9 * Pn;
        int g   = s / gsz;
        int rem = s - g * gsz;
        int p   = rem / 9;
        by = p * 8 + xcd;
        bx = g * 9 + (rem - p * 9);
    }

    const long zb = blockIdx.z;
    A += zb * sAb;
    B += zb * sBb;
    C += zb * sCb;

    const int rowBase = by * 128;
    const int colBase = bx * 128;

    const int g0 = wave * 64 + lane;
    const int r0 = g0 >> 2;
    const int c0 = (g0 & 3) * 8;
    const bf16* a0 = A + (long)(rowBase + r0) * lda + c0;
    const bf16* a1 = A + (long)(rowBase + 64 + r0) * lda + c0;
    const bf16* b0 = B + (long)(colBase + r0) * ldb + c0;
    const bf16* b1 = B + (long)(colBase + 64 + r0) * ldb + c0;
    char* lA = (char*)As + wave * 1024;   // buf stride 8192 B
    char* lB = (char*)Bs + wave * 1024;

    f32x4 acc[4][4] = {};
    const int kt = K >> 5;

    auto stage = [&](int s) {
        char* dA = lA + s * 8192;
        char* dB = lB + s * 8192;
        async_copy16(a0, dA);
        async_copy16(a1, dA + 4096);
        async_copy16(b0, dB);
        async_copy16(b1, dB + 4096);
        a0 += 32; a1 += 32; b0 += 32; b1 += 32;
    };
    auto compute = [&](int s) {
        const bf16* Ab = As[s];
        const bf16* Bb = Bs[s];
        bf16x8 af[4], bfv[4];
#pragma unroll
        for (int t = 0; t < 4; ++t) {
            af[t]  = *(const bf16x8*)(Ab + (wM + t * 16 + l16) * 32 + quad * 8);
            bfv[t] = *(const bf16x8*)(Bb + (wN + t * 16 + l16) * 32 + quad * 8);
        }
#pragma unroll
        for (int mt = 0; mt < 4; ++mt)
#pragma unroll
            for (int nt = 0; nt < 4; ++nt)
                acc[mt][nt] = __builtin_amdgcn_mfma_f32_16x16x32_bf16(
                    af[mt], bfv[nt], acc[mt][nt], 0, 0, 0);
    };

    // prologue: 2 tiles in flight (8 loads/wave)
    stage(0); stage(1);
    int rd = 0, st = 2;
#pragma unroll 1
    for (int k = 0; k < kt - 2; ++k) {
        // wait tile k (leave tile k+1's 4 loads in flight); all waves sync'd
        WAITVM(4);
        WAITLGKM0;
        BAR();
        stage(st);          // overwrite buffer read at iter k-1 (drained above)
        compute(rd);
        rd = rd == 2 ? 0 : rd + 1;
        st = st == 2 ? 0 : st + 1;
    }
    WAITVM(4); WAITLGKM0; BAR(); compute(rd);
    rd = rd == 2 ? 0 : rd + 1;
    WAITVM(0); WAITLGKM0; BAR(); compute(rd);

    // C/D layout: col = lane&15, row = quad*4 + reg  [m89/m91]
#pragma unroll
    for (int mt = 0; mt < 4; ++mt) {
        const int row = rowBase + wM + mt * 16 + quad * 4;
#pragma unroll
        for (int nt = 0; nt < 4; ++nt) {
            const int col = colBase + wN + nt * 16 + l16;
            const float bv = HAS_BIAS ? bias[col] : 0.0f;
#pragma unroll
            for (int r = 0; r < 4; ++r) {
                float v = acc[mt][nt][r] * scale + bv;
                C[(long)(row + r) * ldc + col] = (OutT)v;
            }
        }
    }
}

// Fused scores+softmax: S = x@U^T + c[m]; P = softmax(S*scale).
// Per block: 128 rows x 256 cols of one batch. 512 thr = 8 waves (2x4 of 64x64).
// 4-deep counted-vmcnt pipeline (1 block/CU, 2 waves/SIMD -> in-wave ILP only).
__global__ __launch_bounds__(512) void scores_softmax_k(
    const bf16* __restrict__ X, const bf16* __restrict__ UVW,
    const float* __restrict__ cvec, bf16* __restrict__ P) {
    __shared__ __align__(16) bf16 As[4][128 * 32];   // 32 KB
    __shared__ __align__(16) bf16 Bs[4][256 * 32];   // 64 KB
    __shared__ float red[128][4];
    __shared__ float red2[128][4];
    const int tid  = threadIdx.x;
    const int wave = tid >> 6;
    const int lane = tid & 63;
    const int quad = lane >> 4;
    const int l16  = lane & 15;
    const int wM   = (wave >> 2) * 64;
    const int wN   = (wave & 3) * 64;
    const int wc   = wave & 3;

    int bx = blockIdx.x, by = blockIdx.y;
    {
        int lid = by * 8 + bx;
        int xcd = lid & 7;
        int s   = lid >> 3;
        by = (s >> 3) * 8 + xcd;
        bx = s & 7;
    }
    const long b = by;
    const bf16* A = X + (b * 1024 + (long)bx * 128) * 1152;
    const bf16* B = UVW + b * 256 * 2304;   // U part: cols 0..1151, stride 2304

    const int ra = tid >> 2, ca = (tid & 3) * 8;
    const bf16* a0 = A + (long)ra * 1152 + ca;
    const bf16* b0 = B + (long)ra * 2304 + ca;
    const bf16* b1 = B + (long)(128 + ra) * 2304 + ca;
    char* lA = (char*)As + wave * 1024;   // buf stride 8192 B
    char* lB = (char*)Bs + wave * 1024;   // buf stride 16384 B

    f32x4 acc[4][4] = {};

    auto stage = [&](int s) {
        char* dA = lA + s * 8192;
        char* dB = lB + s * 16384;
        async_copy16(a0, dA);
        async_copy16(b0, dB);
        async_copy16(b1, dB + 8192);
        a0 += 32; b0 += 32; b1 += 32;
    };
    auto compute = [&](int s) {
        const bf16* Ab = As[s];
        const bf16* Bb = Bs[s];
        bf16x8 af[4], bfv[4];
#pragma unroll
        for (int t = 0; t < 4; ++t) {
            af[t]  = *(const bf16x8*)(Ab + (wM + t * 16 + l16) * 32 + quad * 8);
            bfv[t] = *(const bf16x8*)(Bb + (wN + t * 16 + l16) * 32 + quad * 8);
        }
#pragma unroll
        for (int mt = 0; mt < 4; ++mt)
#pragma unroll
            for (int nt = 0; nt < 4; ++nt)
                acc[mt][nt] = __builtin_amdgcn_mfma_f32_16x16x32_bf16(
                    af[mt], bfv[nt], acc[mt][nt], 0, 0, 0);
    };

    // prologue: 3 tiles in flight (9 loads/wave)
    stage(0); stage(1); stage(2);
    int rd = 0, st = 3;
#pragma unroll 1
    for (int k = 0; k < 33; ++k) {
        WAITVM(6);          // tile k landed; tiles k+1,k+2 (6 loads) in flight
        WAITLGKM0;
        BAR();
        stage(st);
        compute(rd);
        rd = (rd + 1) & 3;
        st = (st + 1) & 3;
    }
    WAITVM(6); WAITLGKM0; BAR(); compute(rd); rd = (rd + 1) & 3;
    WAITVM(3); WAITLGKM0; BAR(); compute(rd); rd = (rd + 1) & 3;
    WAITVM(0); WAITLGKM0; BAR(); compute(rd);

    // add m-dependent bias c[m] (part of Q·Km^T)
    float cv[4];
#pragma unroll
    for (int nt = 0; nt < 4; ++nt) cv[nt] = cvec[b * 256 + wN + nt * 16 + l16];
#pragma unroll
    for (int mt = 0; mt < 4; ++mt)
#pragma unroll
        for (int nt = 0; nt < 4; ++nt)
#pragma unroll
            for (int r = 0; r < 4; ++r) acc[mt][nt][r] += cv[nt];

    const float scale = 0.029462782549439484f;  // 1/sqrt(1152)

#pragma unroll
    for (int mt = 0; mt < 4; ++mt)
#pragma unroll
        for (int r = 0; r < 4; ++r) {
            float pm = fmaxf(fmaxf(acc[mt][0][r], acc[mt][1][r]),
                             fmaxf(acc[mt][2][r], acc[mt][3][r]));
#pragma unroll
            for (int off = 1; off <= 8; off <<= 1) pm = fmaxf(pm, __shfl_xor(pm, off));
            if (l16 == 0) red[wM + mt * 16 + quad * 4 + r][wc] = pm;
        }
    __syncthreads();
#pragma unroll
    for (int mt = 0; mt < 4; ++mt)
#pragma unroll
        for (int r = 0; r < 4; ++r) {
            const int R = wM + mt * 16 + quad * 4 + r;
            float4 q = *(const float4*)red[R];
            float m = fmaxf(fmaxf(q.x, q.y), fmaxf(q.z, q.w));
            float ps = 0.0f;
#pragma unroll
            for (int nt = 0; nt < 4; ++nt) {
                float e = __expf((acc[mt][nt][r] - m) * scale);
                acc[mt][nt][r] = e;
                ps += e;
            }
#pragma unroll
            for (int off = 1; off <= 8; off <<= 1) ps += __shfl_xor(ps, off);
            if (l16 == 0) red2[R][wc] = ps;
        }
    __syncthreads();
#pragma unroll
    for (int mt = 0; mt < 4; ++mt)
#pragma unroll
        for (int r = 0; r < 4; ++r) {
            const int R = wM + mt * 16 + quad * 4 + r;
            float4 q = *(const float4*)red2[R];
            float inv = 1.0f / (q.x + q.y + q.z + q.w);
            const long gr = b * 1024 + (long)bx * 128 + R;
#pragma unroll
            for (int nt = 0; nt < 4; ++nt)
                P[gr * 256 + wN + nt * 16 + l16] = (bf16)(acc[mt][nt][r] * inv);
        }
}

// Transpose+cvt fp32->bf16: z=0 Wq->slot0, z=1 Wk->slot2, z=2 Wv->slot3 of WT4.
__global__ void cvt_wT_k(const float* __restrict__ Wq, const float* __restrict__ Wk,
                         const float* __restrict__ Wv, bf16* __restrict__ dst) {
    __shared__ bf16 t[64][66];
    const int z = blockIdx.z;
    const float* src = z == 0 ? Wq : z == 1 ? Wk : Wv;
    bf16* d = dst + (long)(z == 0 ? 0 : z == 1 ? 2 : 3) * 1327104;
    const int r0 = blockIdx.y * 64, c0 = blockIdx.x * 64;
    const int tid = threadIdx.x;
    {
        int row = tid >> 4;
        int col4 = (tid & 15) * 4;
#pragma unroll
        for (int p = 0; p < 4; ++p) {
            int r = row + p * 16;
            float4 v = *(const float4*)(src + (long)(r0 + r) * 1152 + c0 + col4);
            t[col4 + 0][r] = (bf16)v.x;
            t[col4 + 1][r] = (bf16)v.y;
            t[col4 + 2][r] = (bf16)v.z;
            t[col4 + 3][r] = (bf16)v.w;
        }
    }
    __syncthreads();
    {
        int orow = tid >> 2;
        int oc = (tid & 3) * 16;
        bf16x8 a, b2;
#pragma unroll
        for (int j = 0; j < 8; ++j) { a[j] = t[orow][oc + j]; b2[j] = t[orow][oc + 8 + j]; }
        bf16* o = d + (long)(c0 + orow) * 1152 + r0 + oc;
        *(bf16x8*)o = a;
        *(bf16x8*)(o + 8) = b2;
    }
}

// Plain cvt Wo -> WT4 slot 1
__global__ void cvt_w_plain_k(const float* __restrict__ Wo, bf16* __restrict__ dst) {
    int i = blockIdx.x * 256 + threadIdx.x;  // 331776 exact
    float4 v = ((const float4*)Wo)[i];
    bf16x4 o = {(bf16)v.x, (bf16)v.y, (bf16)v.z, (bf16)v.w};
    ((bf16x4*)(dst + 1327104))[i] = o;
}

// x fp32 [32768 x 1152] -> xb bf16 (all rows) + xm bf16 (mean over 4-row windows)
__global__ void cvt_merge_x_k(const float* __restrict__ x, bf16* __restrict__ xb,
                              bf16* __restrict__ xm) {
    int i = blockIdx.x * 256 + threadIdx.x;  // 8192*288 exact
    int w = i / 288;
    int c4 = i - w * 288;
    const float4* p = (const float4*)(x + (long)w * 4608) + c4;
    float4 a = p[0], b = p[288], c = p[576], d = p[864];
    bf16x4 oa = {(bf16)a.x, (bf16)a.y, (bf16)a.z, (bf16)a.w};
    bf16x4 ob = {(bf16)b.x, (bf16)b.y, (bf16)b.z, (bf16)b.w};
    bf16x4 oc = {(bf16)c.x, (bf16)c.y, (bf16)c.z, (bf16)c.w};
    bf16x4 od = {(bf16)d.x, (bf16)d.y, (bf16)d.z, (bf16)d.w};
    bf16* base = xb + (long)w * 4608 + c4 * 4;
    *(bf16x4*)(base)        = oa;
    *(bf16x4*)(base + 1152) = ob;
    *(bf16x4*)(base + 2304) = oc;
    *(bf16x4*)(base + 3456) = od;
    float4 s;
    s.x = (a.x + b.x + c.x + d.x) * 0.25f;
    s.y = (a.y + b.y + c.y + d.y) * 0.25f;
    s.z = (a.z + b.z + c.z + d.z) * 0.25f;
    s.w = (a.w + b.w + c.w + d.w) * 0.25f;
    bf16x4 o = {(bf16)s.x, (bf16)s.y, (bf16)s.z, (bf16)s.w};
    *(bf16x4*)(xm + (long)w * 1152 + c4 * 4) = o;
}

// out[row] = dot(M[row,0:1152], v); optionally zero z[row]. One wave per row.
__global__ void rowdot_k(const bf16* __restrict__ M, const float* __restrict__ v,
                         float* __restrict__ out, float* __restrict__ z) {
    const int row = blockIdx.x * 4 + (threadIdx.x >> 6);
    const int lane = threadIdx.x & 63;
    const bf16* mr = M + (long)row * 1152;
    float acc = 0.0f;
#pragma unroll
    for (int j = 0; j < 18; ++j)
        acc += (float)mr[j * 64 + lane] * v[j * 64 + lane];
#pragma unroll
    for (int off = 32; off; off >>= 1) acc += __shfl_xor(acc, off, 64);
    if (lane == 0) {
        out[row] = acc;
        if (z) z[row] = 0.0f;
    }
}

// VW part of UVW [b*256+m][2304]@+1152 -> VWT:[b][1152][256]
__global__ void transpose_vm_k(const bf16* __restrict__ UVW, bf16* __restrict__ VT) {
    __shared__ bf16 t[64][65];
    const int tid = threadIdx.x;
    const int b = blockIdx.z;
    const int d0 = blockIdx.x * 64, m0 = blockIdx.y * 64;
#pragma unroll
    for (int p = 0; p < 2; ++p) {
        int r = (tid >> 3) + p * 32;
        int c = (tid & 7) * 8;
        bf16x8 v = *(const bf16x8*)(UVW + (long)(b * 256 + m0 + r) * 2304 + 1152 + d0 + c);
#pragma unroll
        for (int j = 0; j < 8; ++j) t[c + j][r] = v[j];
    }
    __syncthreads();
#pragma unroll
    for (int p = 0; p < 2; ++p) {
        int r = (tid >> 3) + p * 32;
        int c = (tid & 7) * 8;
        bf16x8 o;
#pragma unroll
        for (int j = 0; j < 8; ++j) o[j] = t[r][c + j];
        *(bf16x8*)(VT + (long)b * 294912 + (long)(d0 + r) * 256 + m0 + c) = o;
    }
}

extern "C" void kernel_launch(void* const* d_in, const int* in_sizes, int n_in,
                              void* d_out, int out_size, void* d_ws, size_t ws_size,
                              hipStream_t stream) {
    const float* x  = (const float*)d_in[0];
    const float* Wq = (const float*)d_in[1];
    const float* bq = (const float*)d_in[2];
    const float* Wk = (const float*)d_in[3];
    const float* bk = (const float*)d_in[4];  (void)bk;  // softmax-invariant
    const float* Wv = (const float*)d_in[5];
    const float* bv = (const float*)d_in[6];
    const float* Wo = (const float*)d_in[7];
    const float* bo = (const float*)d_in[8];
    float* out = (float*)d_out;
    char* ws = (char*)d_ws;

    // ws layout (~108 MB)
    bf16* WT4    = (bf16*)(ws);                  // [WqT | Wo | WkT | WvT], 10,616,832 B
    bf16* WkT_b  = WT4 + 2 * 1327104;
    bf16* Wo_b   = WT4 + 1 * 1327104;
    bf16* WQK2   = (bf16*)(ws + 10616832);       // [Wqk ; Wvo] [2304x1152], 5,308,416 B
    float* biasUV = (float*)(ws + 15925248);     // [2304] = [0 | Wo·bv]
    float* vk     = (float*)(ws + 15934464);     // [1152] = Wk^T·bq
    float* cvec   = (float*)(ws + 15939072);     // [8192] = x_m·vk
    bf16* xm_b   = (bf16*)(ws + 15971840);       // [8192x1152], 18,874,368 B
    bf16* UVW    = (bf16*)(ws + 34846208);       // [8192x2304], 37,748,736 B
    bf16* VWT    = (bf16*)(ws + 72594944);       // [32][1152][256], 18,874,368 B
    bf16* P_b    = (bf16*)(ws + 91469312);       // [32768x256], 16,777,216 B

    // d_out (151 MB fp32) as scratch for x_b; dead before final GEMM writes out.
    bf16* x_b = (bf16*)d_out;                    // 75,497,472 B

    // 1. weight prep: WqT, WkT, WvT (transposed) + Wo (plain), all bf16
    cvt_wT_k<<<dim3(18, 18, 3), 256, 0, stream>>>(Wq, Wk, Wv, WT4);
    cvt_w_plain_k<<<1296, 256, 0, stream>>>(Wo, WT4);
    cvt_merge_x_k<<<9216, 256, 0, stream>>>(x, x_b, xm_b);

    // 2. Wqk = WqT·WkT^T = Wq^T·Wk (z=0); Wvo = Wo·WvT^T = Wo·Wv (z=1)
    gemm_bt<bf16, false><<<dim3(9, 9, 2), 256, 0, stream>>>(
        WT4, WT4 + 2 * 1327104, nullptr, WQK2,
        1152, 1152, 1152, 1152, 1152, 1.0f, 1327104, 1327104, 1327104);

    // 3. small vectors: vk = WkT·bq (also zero biasUV[0:1152]); biasUV[1152:] = Wo·bv
    rowdot_k<<<288, 256, 0, stream>>>(WkT_b, bq, vk, biasUV);
    rowdot_k<<<288, 256, 0, stream>>>(Wo_b, bv, biasUV + 1152, nullptr);

    // 4. [U | VW] = x_m @ WQK2^T + biasUV
    gemm_bt<bf16, true><<<dim3(18, 64, 1), 256, 0, stream>>>(
        xm_b, WQK2, biasUV, UVW, 2304, 1152, 1152, 1152, 2304, 1.0f, 0, 0, 0);

    // 5. c[m] = x_m · vk
    rowdot_k<<<2048, 256, 0, stream>>>(xm_b, vk, cvec, nullptr);

    // 6. VWT = transpose(VW) per batch
    transpose_vm_k<<<dim3(18, 4, 32), 256, 0, stream>>>(UVW, VWT);

    // 7. P = softmax((x@U^T + c)/sqrt(D))
    scores_softmax_k<<<dim3(8, 32), 512, 0, stream>>>(x_b, UVW, cvec, P_b);

    // 8. out = P @ VWT^T + bo (fp32)
    gemm_bt<float, true><<<dim3(9, 8, 32), 256, 0, stream>>>(
        P_b, VWT, bo, out, 1152, 256, 256, 256, 1152, 1.0f,
        1024L * 256, 1152L * 256, 1024L * 1152);
}

// Round 3
// 489.333 us; speedup vs baseline: 1.0197x; 1.0197x over previous
//
#include <hip/hip_runtime.h>
#include <hip/hip_bf16.h>

// SiglipSdpaAttention: B=32, N=1024, D=1152, R=4, M=N/R=256.
// Algebra: merge commutes with projections; softmax drops row-constant terms.
//   S = Q@Km^T: expand -> x·(Wq^T Wk)·x_m^T + c[m],  c = x_m·(Wk^T bq)
//   out = P·Vm·Wo^T + bo = P·(x_m·(Wo Wv)^T + Wo bv) + bo
//   [U | VW] = x_m @ [Wqk ; Wvo]^T + [0 | Wo·bv],  Wqk=Wq^T·Wk, Wvo=Wo·Wv
//   P = softmax((x@U^T + c[m]) / sqrt(D));  out = P@VW + bo
// Total ~88 GFLOP. GEMMs bf16 MFMA 16x16x32, 128x128 tile, global_load_lds
// width-16 staging, XCD swizzle.
// R3: (a) scores kernel re-tiled 128->64 rows: grid 256->512 blocks, 256 thr,
//     43 KB LDS -> 2-3 independent blocks/CU so barrier drains overlap with
//     another block's MFMA (was 1 block/CU lockstep = zero overlap).
//     (b) dispatch count 13->9 (cvt_w_plain folded into cvt_wT z=3; weight
//     rowdots merged into one z-indexed launch). gemm_bt reverted to R1
//     2-buffer form (R2 counted-vmcnt was neutral-negative).

typedef __bf16 bf16;
typedef __attribute__((ext_vector_type(8))) __bf16 bf16x8;
typedef __attribute__((ext_vector_type(4))) __bf16 bf16x4;
typedef __attribute__((ext_vector_type(4))) float f32x4;

#define GAS __attribute__((address_space(1)))
#define LAS __attribute__((address_space(3)))

__device__ __forceinline__ void async_copy16(const void* g, void* s) {
    __builtin_amdgcn_global_load_lds((GAS unsigned int*)g, (LAS unsigned int*)s, 16, 0, 0);
}

// C = A * B^T (+bias) * scale. A:[M x K] rowmajor (lda), B:[N x K] rowmajor (ldb),
// C:[M x N] (ldc). Tile 128x128, BK=32, 256 thr = 4 waves (2x2 of 64x64).
// Double-buffered: stage k+1 while computing k; one barrier per K-iter.
template <typename OutT, bool HAS_BIAS>
__global__ __launch_bounds__(256) void gemm_bt(
    const bf16* __restrict__ A, const bf16* __restrict__ B,
    const float* __restrict__ bias, OutT* __restrict__ C,
    int N, int K, int lda, int ldb, int ldc, float scale,
    long sAb, long sBb, long sCb) {
    __shared__ __align__(16) bf16 As[2][128 * 32];
    __shared__ __align__(16) bf16 Bs[2][128 * 32];
    const int tid  = threadIdx.x;
    const int wave = tid >> 6;
    const int lane = tid & 63;
    const int quad = lane >> 4;
    const int l16  = lane & 15;
    const int wM   = (wave >> 1) * 64;
    const int wN   = (wave & 1) * 64;

    // XCD swizzle: all x-tiles of an A-panel on one XCD (A fetched once/panel).
    int bx = blockIdx.x, by = blockIdx.y;
    const int nbx = gridDim.x, nby = gridDim.y;
    if (((nby & 7) == 0) && (nbx % 9 == 0)) {
        int lid = by * nbx + bx;
        int xcd = lid & 7;
        int s   = lid >> 3;
        int Pn  = nby >> 3;
        int gsz = 9 * Pn;
        int g   = s / gsz;
        int rem = s - g * gsz;
        int p   = rem / 9;
        by = p * 8 + xcd;
        bx = g * 9 + (rem - p * 9);
    }

    const long zb = blockIdx.z;
    A += zb * sAb;
    B += zb * sBb;
    C += zb * sCb;

    const int rowBase = by * 128;
    const int colBase = bx * 128;

    const int g0 = wave * 64 + lane;
    const int r0 = g0 >> 2;
    const int c0 = (g0 & 3) * 8;
    const bf16* a0 = A + (long)(rowBase + r0) * lda + c0;
    const bf16* a1 = A + (long)(rowBase + 64 + r0) * lda + c0;
    const bf16* b0 = B + (long)(colBase + r0) * ldb + c0;
    const bf16* b1 = B + (long)(colBase + 64 + r0) * ldb + c0;
    char* lA = (char*)As + wave * 1024;   // buf stride 8192 B
    char* lB = (char*)Bs + wave * 1024;

    f32x4 acc[4][4] = {};

    const int kt = K >> 5;
    // prologue: stage tile 0 into buf 0
    async_copy16(a0, lA);
    async_copy16(a1, lA + 4096);
    async_copy16(b0, lB);
    async_copy16(b1, lB + 4096);
    a0 += 32; a1 += 32; b0 += 32; b1 += 32;
    int cur = 0;
    for (int k = 0; k < kt; ++k) {
        // drains vmcnt(0): stage of buf[cur] landed; all waves done reading buf[cur^1]
        __syncthreads();
        if (k + 1 < kt) {
            char* nA = lA + ((cur ^ 1) << 13);
            char* nB = lB + ((cur ^ 1) << 13);
            async_copy16(a0, nA);
            async_copy16(a1, nA + 4096);
            async_copy16(b0, nB);
            async_copy16(b1, nB + 4096);
            a0 += 32; a1 += 32; b0 += 32; b1 += 32;
        }
        const bf16* Ab = &As[cur][0];
        const bf16* Bb = &Bs[cur][0];
        bf16x8 af[4], bfv[4];
#pragma unroll
        for (int t = 0; t < 4; ++t) {
            af[t]  = *(const bf16x8*)(Ab + (wM + t * 16 + l16) * 32 + quad * 8);
            bfv[t] = *(const bf16x8*)(Bb + (wN + t * 16 + l16) * 32 + quad * 8);
        }
#pragma unroll
        for (int mt = 0; mt < 4; ++mt)
#pragma unroll
            for (int nt = 0; nt < 4; ++nt)
                acc[mt][nt] = __builtin_amdgcn_mfma_f32_16x16x32_bf16(
                    af[mt], bfv[nt], acc[mt][nt], 0, 0, 0);
        cur ^= 1;
    }

    // C/D layout: col = lane&15, row = quad*4 + reg  [m89/m91]
#pragma unroll
    for (int mt = 0; mt < 4; ++mt) {
        const int row = rowBase + wM + mt * 16 + quad * 4;
#pragma unroll
        for (int nt = 0; nt < 4; ++nt) {
            const int col = colBase + wN + nt * 16 + l16;
            const float bv = HAS_BIAS ? bias[col] : 0.0f;
#pragma unroll
            for (int r = 0; r < 4; ++r) {
                float v = acc[mt][nt][r] * scale + bv;
                C[(long)(row + r) * ldc + col] = (OutT)v;
            }
        }
    }
}

// Fused scores+softmax: S = x@U^T + c[m]; P = softmax(S*scale).
// Per block: 64 rows x 256 cols of one batch. 256 thr = 4 waves (1x4 of 64x64).
// Grid 512 blocks, 43 KB LDS -> 2-3 independent blocks/CU (inter-block overlap
// hides the per-iter barrier drain; was 1 block/CU lockstep).
__global__ __launch_bounds__(256) void scores_softmax_k(
    const bf16* __restrict__ X, const bf16* __restrict__ UVW,
    const float* __restrict__ cvec, bf16* __restrict__ P) {
    __shared__ __align__(16) bf16 As[2][64 * 32];    // 8 KB
    __shared__ __align__(16) bf16 Bs[2][256 * 32];   // 32 KB
    __shared__ float red[64][4];
    __shared__ float red2[64][4];
    const int tid  = threadIdx.x;
    const int wave = tid >> 6;
    const int lane = tid & 63;
    const int quad = lane >> 4;
    const int l16  = lane & 15;
    const int wN   = wave * 64;
    const int wc   = wave;

    // XCD swizzle: 512 blocks; same-batch blocks grouped per XCD (U-panel reuse).
    int bx = blockIdx.x, by = blockIdx.y;
    {
        int lid = by * 16 + bx;
        int xcd = lid & 7;
        int s   = lid >> 3;
        by = (s >> 4) * 8 + xcd;
        bx = s & 15;
    }
    const long b = by;
    const bf16* A = X + (b * 1024 + (long)bx * 64) * 1152;
    const bf16* B = UVW + b * 256 * 2304;   // U part: cols 0..1151, stride 2304

    const int ra = tid >> 2, ca = (tid & 3) * 8;   // ra 0..63
    const bf16* a0 = A + (long)ra * 1152 + ca;
    const bf16* b0 = B + (long)ra * 2304 + ca;
    const bf16* b1 = B + (long)(64 + ra) * 2304 + ca;
    const bf16* b2 = B + (long)(128 + ra) * 2304 + ca;
    const bf16* b3 = B + (long)(192 + ra) * 2304 + ca;
    char* lA = (char*)As + wave * 1024;   // buf stride 4096 B
    char* lB = (char*)Bs + wave * 1024;   // buf stride 16384 B, row-group stride 4096

    f32x4 acc[4][4] = {};
    // prologue: stage tile 0 into buf 0
    async_copy16(a0, lA);
    async_copy16(b0, lB);
    async_copy16(b1, lB + 4096);
    async_copy16(b2, lB + 8192);
    async_copy16(b3, lB + 12288);
    a0 += 32; b0 += 32; b1 += 32; b2 += 32; b3 += 32;
    int cur = 0;
#pragma unroll 1
    for (int k = 0; k < 36; ++k) {
        __syncthreads();
        if (k < 35) {
            char* nA = lA + ((cur ^ 1) << 12);
            char* nB = lB + ((cur ^ 1) << 14);
            async_copy16(a0, nA);
            async_copy16(b0, nB);
            async_copy16(b1, nB + 4096);
            async_copy16(b2, nB + 8192);
            async_copy16(b3, nB + 12288);
            a0 += 32; b0 += 32; b1 += 32; b2 += 32; b3 += 32;
        }
        const bf16* Ab = &As[cur][0];
        const bf16* Bb = &Bs[cur][0];
        bf16x8 af[4], bfv[4];
#pragma unroll
        for (int t = 0; t < 4; ++t) {
            af[t]  = *(const bf16x8*)(Ab + (t * 16 + l16) * 32 + quad * 8);
            bfv[t] = *(const bf16x8*)(Bb + (wN + t * 16 + l16) * 32 + quad * 8);
        }
#pragma unroll
        for (int mt = 0; mt < 4; ++mt)
#pragma unroll
            for (int nt = 0; nt < 4; ++nt)
                acc[mt][nt] = __builtin_amdgcn_mfma_f32_16x16x32_bf16(
                    af[mt], bfv[nt], acc[mt][nt], 0, 0, 0);
        cur ^= 1;
    }

    // add m-dependent bias c[m] (part of Q·Km^T)
    float cv[4];
#pragma unroll
    for (int nt = 0; nt < 4; ++nt) cv[nt] = cvec[b * 256 + wN + nt * 16 + l16];
#pragma unroll
    for (int mt = 0; mt < 4; ++mt)
#pragma unroll
        for (int nt = 0; nt < 4; ++nt)
#pragma unroll
            for (int r = 0; r < 4; ++r) acc[mt][nt][r] += cv[nt];

    const float scale = 0.029462782549439484f;  // 1/sqrt(1152)

#pragma unroll
    for (int mt = 0; mt < 4; ++mt)
#pragma unroll
        for (int r = 0; r < 4; ++r) {
            float pm = fmaxf(fmaxf(acc[mt][0][r], acc[mt][1][r]),
                             fmaxf(acc[mt][2][r], acc[mt][3][r]));
#pragma unroll
            for (int off = 1; off <= 8; off <<= 1) pm = fmaxf(pm, __shfl_xor(pm, off));
            if (l16 == 0) red[mt * 16 + quad * 4 + r][wc] = pm;
        }
    __syncthreads();
#pragma unroll
    for (int mt = 0; mt < 4; ++mt)
#pragma unroll
        for (int r = 0; r < 4; ++r) {
            const int R = mt * 16 + quad * 4 + r;
            float4 q = *(const float4*)red[R];
            float m = fmaxf(fmaxf(q.x, q.y), fmaxf(q.z, q.w));
            float ps = 0.0f;
#pragma unroll
            for (int nt = 0; nt < 4; ++nt) {
                float e = __expf((acc[mt][nt][r] - m) * scale);
                acc[mt][nt][r] = e;
                ps += e;
            }
#pragma unroll
            for (int off = 1; off <= 8; off <<= 1) ps += __shfl_xor(ps, off);
            if (l16 == 0) red2[R][wc] = ps;
        }
    __syncthreads();
#pragma unroll
    for (int mt = 0; mt < 4; ++mt)
#pragma unroll
        for (int r = 0; r < 4; ++r) {
            const int R = mt * 16 + quad * 4 + r;
            float4 q = *(const float4*)red2[R];
            float inv = 1.0f / (q.x + q.y + q.z + q.w);
            const long gr = b * 1024 + (long)bx * 64 + R;
#pragma unroll
            for (int nt = 0; nt < 4; ++nt)
                P[gr * 256 + wN + nt * 16 + l16] = (bf16)(acc[mt][nt][r] * inv);
        }
}

// Weight prep: z=0 Wq->slot0 (T), z=1 Wk->slot2 (T), z=2 Wv->slot3 (T),
// z=3 Wo->slot1 (plain). All fp32->bf16.
__global__ void cvt_wT_k(const float* __restrict__ Wq, const float* __restrict__ Wk,
                         const float* __restrict__ Wv, const float* __restrict__ Wo,
                         bf16* __restrict__ dst) {
    const int z = blockIdx.z;
    const int r0 = blockIdx.y * 64, c0 = blockIdx.x * 64;
    const int tid = threadIdx.x;
    if (z == 3) {
        // plain copy Wo -> slot 1
        int row = tid >> 2;
        int col = (tid & 3) * 16;
        const float* s = Wo + (long)(r0 + row) * 1152 + c0 + col;
        bf16* d = dst + 1327104 + (long)(r0 + row) * 1152 + c0 + col;
#pragma unroll
        for (int j = 0; j < 4; ++j) {
            float4 v = ((const float4*)s)[j];
            bf16x4 o = {(bf16)v.x, (bf16)v.y, (bf16)v.z, (bf16)v.w};
            ((bf16x4*)d)[j] = o;
        }
        return;
    }
    __shared__ bf16 t[64][66];
    const float* src = z == 0 ? Wq : z == 1 ? Wk : Wv;
    bf16* d = dst + (long)(z == 0 ? 0 : z == 1 ? 2 : 3) * 1327104;
    {
        int row = tid >> 4;
        int col4 = (tid & 15) * 4;
#pragma unroll
        for (int p = 0; p < 4; ++p) {
            int r = row + p * 16;
            float4 v = *(const float4*)(src + (long)(r0 + r) * 1152 + c0 + col4);
            t[col4 + 0][r] = (bf16)v.x;
            t[col4 + 1][r] = (bf16)v.y;
            t[col4 + 2][r] = (bf16)v.z;
            t[col4 + 3][r] = (bf16)v.w;
        }
    }
    __syncthreads();
    {
        int orow = tid >> 2;
        int oc = (tid & 3) * 16;
        bf16x8 a, b2;
#pragma unroll
        for (int j = 0; j < 8; ++j) { a[j] = t[orow][oc + j]; b2[j] = t[orow][oc + 8 + j]; }
        bf16* o = d + (long)(c0 + orow) * 1152 + r0 + oc;
        *(bf16x8*)o = a;
        *(bf16x8*)(o + 8) = b2;
    }
}

// x fp32 [32768 x 1152] -> xb bf16 (all rows) + xm bf16 (mean over 4-row windows)
__global__ void cvt_merge_x_k(const float* __restrict__ x, bf16* __restrict__ xb,
                              bf16* __restrict__ xm) {
    int i = blockIdx.x * 256 + threadIdx.x;  // 8192*288 exact
    int w = i / 288;
    int c4 = i - w * 288;
    const float4* p = (const float4*)(x + (long)w * 4608) + c4;
    float4 a = p[0], b = p[288], c = p[576], d = p[864];
    bf16x4 oa = {(bf16)a.x, (bf16)a.y, (bf16)a.z, (bf16)a.w};
    bf16x4 ob = {(bf16)b.x, (bf16)b.y, (bf16)b.z, (bf16)b.w};
    bf16x4 oc = {(bf16)c.x, (bf16)c.y, (bf16)c.z, (bf16)c.w};
    bf16x4 od = {(bf16)d.x, (bf16)d.y, (bf16)d.z, (bf16)d.w};
    bf16* base = xb + (long)w * 4608 + c4 * 4;
    *(bf16x4*)(base)        = oa;
    *(bf16x4*)(base + 1152) = ob;
    *(bf16x4*)(base + 2304) = oc;
    *(bf16x4*)(base + 3456) = od;
    float4 s;
    s.x = (a.x + b.x + c.x + d.x) * 0.25f;
    s.y = (a.y + b.y + c.y + d.y) * 0.25f;
    s.z = (a.z + b.z + c.z + d.z) * 0.25f;
    s.w = (a.w + b.w + c.w + d.w) * 0.25f;
    bf16x4 o = {(bf16)s.x, (bf16)s.y, (bf16)s.z, (bf16)s.w};
    *(bf16x4*)(xm + (long)w * 1152 + c4 * 4) = o;
}

// Merged weight rowdots: z=0: vk=WkT·bq (+zero biasUV[row]); z=1: biasUV[1152+row]=Wo·bv
__global__ void rowdot2_k(const bf16* __restrict__ WkT, const bf16* __restrict__ Wo_b,
                          const float* __restrict__ bq, const float* __restrict__ bv,
                          float* __restrict__ vk, float* __restrict__ biasUV) {
    const int z = blockIdx.y;
    const bf16* M = z ? Wo_b : WkT;
    const float* v = z ? bv : bq;
    const int row = blockIdx.x * 4 + (threadIdx.x >> 6);
    const int lane = threadIdx.x & 63;
    const bf16* mr = M + (long)row * 1152;
    float acc = 0.0f;
#pragma unroll
    for (int j = 0; j < 18; ++j)
        acc += (float)mr[j * 64 + lane] * v[j * 64 + lane];
#pragma unroll
    for (int off = 32; off; off >>= 1) acc += __shfl_xor(acc, off, 64);
    if (lane == 0) {
        if (z) biasUV[1152 + row] = acc;
        else { vk[row] = acc; biasUV[row] = 0.0f; }
    }
}

// out[row] = dot(M[row,0:1152], v). One wave per row.
__global__ void rowdot_k(const bf16* __restrict__ M, const float* __restrict__ v,
                         float* __restrict__ out) {
    const int row = blockIdx.x * 4 + (threadIdx.x >> 6);
    const int lane = threadIdx.x & 63;
    const bf16* mr = M + (long)row * 1152;
    float acc = 0.0f;
#pragma unroll
    for (int j = 0; j < 18; ++j)
        acc += (float)mr[j * 64 + lane] * v[j * 64 + lane];
#pragma unroll
    for (int off = 32; off; off >>= 1) acc += __shfl_xor(acc, off, 64);
    if (lane == 0) out[row] = acc;
}

// VW part of UVW [b*256+m][2304]@+1152 -> VWT:[b][1152][256]
__global__ void transpose_vm_k(const bf16* __restrict__ UVW, bf16* __restrict__ VT) {
    __shared__ bf16 t[64][65];
    const int tid = threadIdx.x;
    const int b = blockIdx.z;
    const int d0 = blockIdx.x * 64, m0 = blockIdx.y * 64;
#pragma unroll
    for (int p = 0; p < 2; ++p) {
        int r = (tid >> 3) + p * 32;
        int c = (tid & 7) * 8;
        bf16x8 v = *(const bf16x8*)(UVW + (long)(b * 256 + m0 + r) * 2304 + 1152 + d0 + c);
#pragma unroll
        for (int j = 0; j < 8; ++j) t[c + j][r] = v[j];
    }
    __syncthreads();
#pragma unroll
    for (int p = 0; p < 2; ++p) {
        int r = (tid >> 3) + p * 32;
        int c = (tid & 7) * 8;
        bf16x8 o;
#pragma unroll
        for (int j = 0; j < 8; ++j) o[j] = t[r][c + j];
        *(bf16x8*)(VT + (long)b * 294912 + (long)(d0 + r) * 256 + m0 + c) = o;
    }
}

extern "C" void kernel_launch(void* const* d_in, const int* in_sizes, int n_in,
                              void* d_out, int out_size, void* d_ws, size_t ws_size,
                              hipStream_t stream) {
    const float* x  = (const float*)d_in[0];
    const float* Wq = (const float*)d_in[1];
    const float* bq = (const float*)d_in[2];
    const float* Wk = (const float*)d_in[3];
    const float* bk = (const float*)d_in[4];  (void)bk;  // softmax-invariant
    const float* Wv = (const float*)d_in[5];
    const float* bv = (const float*)d_in[6];
    const float* Wo = (const float*)d_in[7];
    const float* bo = (const float*)d_in[8];
    float* out = (float*)d_out;
    char* ws = (char*)d_ws;

    // ws layout (~108 MB)
    bf16* WT4    = (bf16*)(ws);                  // [WqT | Wo | WkT | WvT], 10,616,832 B
    bf16* WkT_b  = WT4 + 2 * 1327104;
    bf16* Wo_b   = WT4 + 1 * 1327104;
    bf16* WQK2   = (bf16*)(ws + 10616832);       // [Wqk ; Wvo] [2304x1152], 5,308,416 B
    float* biasUV = (float*)(ws + 15925248);     // [2304] = [0 | Wo·bv]
    float* vk     = (float*)(ws + 15934464);     // [1152] = Wk^T·bq
    float* cvec   = (float*)(ws + 15939072);     // [8192] = x_m·vk
    bf16* xm_b   = (bf16*)(ws + 15971840);       // [8192x1152], 18,874,368 B
    bf16* UVW    = (bf16*)(ws + 34846208);       // [8192x2304], 37,748,736 B
    bf16* VWT    = (bf16*)(ws + 72594944);       // [32][1152][256], 18,874,368 B
    bf16* P_b    = (bf16*)(ws + 91469312);       // [32768x256], 16,777,216 B

    // d_out (151 MB fp32) as scratch for x_b; dead before final GEMM writes out.
    bf16* x_b = (bf16*)d_out;                    // 75,497,472 B

    // 1. weight prep: WqT, WkT, WvT (transposed) + Wo (plain), all bf16
    cvt_wT_k<<<dim3(18, 18, 4), 256, 0, stream>>>(Wq, Wk, Wv, Wo, WT4);
    cvt_merge_x_k<<<9216, 256, 0, stream>>>(x, x_b, xm_b);

    // 2. small vectors: vk = WkT·bq (+zero biasUV[0:1152]); biasUV[1152:] = Wo·bv
    rowdot2_k<<<dim3(288, 2), 256, 0, stream>>>(WkT_b, Wo_b, bq, bv, vk, biasUV);

    // 3. c[m] = x_m · vk
    rowdot_k<<<2048, 256, 0, stream>>>(xm_b, vk, cvec);

    // 4. Wqk = WqT·WkT^T = Wq^T·Wk (z=0); Wvo = Wo·WvT^T = Wo·Wv (z=1)
    gemm_bt<bf16, false><<<dim3(9, 9, 2), 256, 0, stream>>>(
        WT4, WT4 + 2 * 1327104, nullptr, WQK2,
        1152, 1152, 1152, 1152, 1152, 1.0f, 1327104, 1327104, 1327104);

    // 5. [U | VW] = x_m @ WQK2^T + biasUV
    gemm_bt<bf16, true><<<dim3(18, 64, 1), 256, 0, stream>>>(
        xm_b, WQK2, biasUV, UVW, 2304, 1152, 1152, 1152, 2304, 1.0f, 0, 0, 0);

    // 6. VWT = transpose(VW) per batch
    transpose_vm_k<<<dim3(18, 4, 32), 256, 0, stream>>>(UVW, VWT);

    // 7. P = softmax((x@U^T + c)/sqrt(D))  — 64-row tiles, 512 blocks
    scores_softmax_k<<<dim3(16, 32), 256, 0, stream>>>(x_b, UVW, cvec, P_b);

    // 8. out = P @ VWT^T + bo (fp32)
    gemm_bt<float, true><<<dim3(9, 8, 32), 256, 0, stream>>>(
        P_b, VWT, bo, out, 1152, 256, 256, 256, 1152, 1.0f,
        1024L * 256, 1152L * 256, 1024L * 1152);
}

// Round 4
// 465.901 us; speedup vs baseline: 1.0709x; 1.0503x over previous
//
#include <hip/hip_runtime.h>
#include <hip/hip_bf16.h>

// SiglipSdpaAttention: B=32, N=1024, D=1152, R=4, M=N/R=256.
// Algebra: merge commutes with projections; softmax drops row-constant terms.
//   S = Q@Km^T: expand -> x·(Wq^T Wk)·x_m^T + c[m],  c = x_m·(Wk^T bq)
//   out = P·Vm·Wo^T + bo = P·(x_m·(Wo Wv)^T + Wo bv) + bo
//   [U | VW] = x_m @ [Wqk ; Wvo]^T + [0 | Wo·bv],  Wqk=Wq^T·Wk, Wvo=Wo·Wv
//   P = softmax((x@U^T + c[m]) / sqrt(D));  out = P@VW + bo
// Total ~88 GFLOP. GEMMs bf16 MFMA 16x16x32, 128x128 tile, global_load_lds
// width-16 staging, XCD swizzle.
// R4: FUSE steps 7+8: scores+softmax+PV in one kernel (attn_k). P stays in
//     LDS (stride 544 B = 4-way-conflict-free A-frag reads); PV streams VWT
//     tiles like gemm_bt's B operand; writes out fp32 + bo directly.
//     Removes: step-8 GEMM dispatch (K=256, worst-amortized), P round-trip
//     (33.5 MB), one device-wide drain. x_b is scattered into d_out so each
//     block's out-writes only overlap its OWN x-tile (read before write,
//     program order) -> race-free without growing ws.

typedef __bf16 bf16;
typedef __attribute__((ext_vector_type(8))) __bf16 bf16x8;
typedef __attribute__((ext_vector_type(4))) __bf16 bf16x4;
typedef __attribute__((ext_vector_type(4))) float f32x4;

#define GAS __attribute__((address_space(1)))
#define LAS __attribute__((address_space(3)))

__device__ __forceinline__ void async_copy16(const void* g, void* s) {
    __builtin_amdgcn_global_load_lds((GAS unsigned int*)g, (LAS unsigned int*)s, 16, 0, 0);
}

// C = A * B^T (+bias) * scale. A:[M x K] rowmajor (lda), B:[N x K] rowmajor (ldb),
// C:[M x N] (ldc). Tile 128x128, BK=32, 256 thr = 4 waves (2x2 of 64x64).
// Double-buffered: stage k+1 while computing k; one barrier per K-iter.
template <typename OutT, bool HAS_BIAS>
__global__ __launch_bounds__(256) void gemm_bt(
    const bf16* __restrict__ A, const bf16* __restrict__ B,
    const float* __restrict__ bias, OutT* __restrict__ C,
    int N, int K, int lda, int ldb, int ldc, float scale,
    long sAb, long sBb, long sCb) {
    __shared__ __align__(16) bf16 As[2][128 * 32];
    __shared__ __align__(16) bf16 Bs[2][128 * 32];
    const int tid  = threadIdx.x;
    const int wave = tid >> 6;
    const int lane = tid & 63;
    const int quad = lane >> 4;
    const int l16  = lane & 15;
    const int wM   = (wave >> 1) * 64;
    const int wN   = (wave & 1) * 64;

    // XCD swizzle: all x-tiles of an A-panel on one XCD (A fetched once/panel).
    int bx = blockIdx.x, by = blockIdx.y;
    const int nbx = gridDim.x, nby = gridDim.y;
    if (((nby & 7) == 0) && (nbx % 9 == 0)) {
        int lid = by * nbx + bx;
        int xcd = lid & 7;
        int s   = lid >> 3;
        int Pn  = nby >> 3;
        int gsz = 9 * Pn;
        int g   = s / gsz;
        int rem = s - g * gsz;
        int p   = rem / 9;
        by = p * 8 + xcd;
        bx = g * 9 + (rem - p * 9);
    }

    const long zb = blockIdx.z;
    A += zb * sAb;
    B += zb * sBb;
    C += zb * sCb;

    const int rowBase = by * 128;
    const int colBase = bx * 128;

    const int g0 = wave * 64 + lane;
    const int r0 = g0 >> 2;
    const int c0 = (g0 & 3) * 8;
    const bf16* a0 = A + (long)(rowBase + r0) * lda + c0;
    const bf16* a1 = A + (long)(rowBase + 64 + r0) * lda + c0;
    const bf16* b0 = B + (long)(colBase + r0) * ldb + c0;
    const bf16* b1 = B + (long)(colBase + 64 + r0) * ldb + c0;
    char* lA = (char*)As + wave * 1024;   // buf stride 8192 B
    char* lB = (char*)Bs + wave * 1024;

    f32x4 acc[4][4] = {};

    const int kt = K >> 5;
    // prologue: stage tile 0 into buf 0
    async_copy16(a0, lA);
    async_copy16(a1, lA + 4096);
    async_copy16(b0, lB);
    async_copy16(b1, lB + 4096);
    a0 += 32; a1 += 32; b0 += 32; b1 += 32;
    int cur = 0;
    for (int k = 0; k < kt; ++k) {
        // drains vmcnt(0): stage of buf[cur] landed; all waves done reading buf[cur^1]
        __syncthreads();
        if (k + 1 < kt) {
            char* nA = lA + ((cur ^ 1) << 13);
            char* nB = lB + ((cur ^ 1) << 13);
            async_copy16(a0, nA);
            async_copy16(a1, nA + 4096);
            async_copy16(b0, nB);
            async_copy16(b1, nB + 4096);
            a0 += 32; a1 += 32; b0 += 32; b1 += 32;
        }
        const bf16* Ab = &As[cur][0];
        const bf16* Bb = &Bs[cur][0];
        bf16x8 af[4], bfv[4];
#pragma unroll
        for (int t = 0; t < 4; ++t) {
            af[t]  = *(const bf16x8*)(Ab + (wM + t * 16 + l16) * 32 + quad * 8);
            bfv[t] = *(const bf16x8*)(Bb + (wN + t * 16 + l16) * 32 + quad * 8);
        }
#pragma unroll
        for (int mt = 0; mt < 4; ++mt)
#pragma unroll
            for (int nt = 0; nt < 4; ++nt)
                acc[mt][nt] = __builtin_amdgcn_mfma_f32_16x16x32_bf16(
                    af[mt], bfv[nt], acc[mt][nt], 0, 0, 0);
        cur ^= 1;
    }

    // C/D layout: col = lane&15, row = quad*4 + reg  [m89/m91]
#pragma unroll
    for (int mt = 0; mt < 4; ++mt) {
        const int row = rowBase + wM + mt * 16 + quad * 4;
#pragma unroll
        for (int nt = 0; nt < 4; ++nt) {
            const int col = colBase + wN + nt * 16 + l16;
            const float bv = HAS_BIAS ? bias[col] : 0.0f;
#pragma unroll
            for (int r = 0; r < 4; ++r) {
                float v = acc[mt][nt][r] * scale + bv;
                C[(long)(row + r) * ldc + col] = (OutT)v;
            }
        }
    }
}

// Fused scores+softmax+PV: per block 64 q-rows of one batch.
//   Phase 1: S = x@U^T + c[m]  (64x256, acc in regs; wave w holds cols 64w..64w+64)
//   Phase 2: softmax -> P (bf16) into LDS [64 rows][256 m], row stride 544 B
//   Phase 3: out = P @ VWT^T + bo  (K=256, d-chunks of 128, VWT staged to LDS)
// Xb (scattered in d_out at block_k*294912+147456) and out alias the same
// buffer: block k only overwrites its OWN x region (read fully in phase 1).
// 256 thr = 4 waves. LDS 53,248 B -> 3 blocks/CU.
__global__ __launch_bounds__(256) void attn_k(
    const bf16* Xb, const bf16* __restrict__ UVW, const bf16* __restrict__ VWT,
    const float* __restrict__ cvec, const float* __restrict__ bo, float* out) {
    // smem map:
    //   phase1: As 2x4096 at [0,8192); Bs 2x16384 at [8192,40960)
    //   phase3: P_lds 64x544 at [0,34816); pB 2x8192 at [34816,51200)
    //   red at [51200,52224); red2 at [52224,53248)
    __shared__ __align__(16) char smem[53248];
    float* red  = (float*)(smem + 51200);
    float* red2 = (float*)(smem + 52224);

    const int tid  = threadIdx.x;
    const int wave = tid >> 6;
    const int lane = tid & 63;
    const int quad = lane >> 4;
    const int l16  = lane & 15;
    const int wN   = wave * 64;

    // XCD swizzle: 512 blocks; same-batch blocks grouped per XCD (U-panel reuse).
    int bx = blockIdx.x, by = blockIdx.y;
    {
        int lid = by * 16 + bx;
        int xcd = lid & 7;
        int s   = lid >> 3;
        by = (s >> 4) * 8 + xcd;
        bx = s & 15;
    }
    const long b = by;
    const int blk = (int)b * 16 + bx;
    const bf16* A = Xb + (long)blk * 147456 + 73728;     // 64 rows x 1152, stride 1152
    const bf16* B = UVW + b * 256 * 2304;   // U part: cols 0..1151, stride 2304
    const bf16* VWTb = VWT + b * 294912;    // [1152 d][256 m]

    const int ra = tid >> 2, ca = (tid & 3) * 8;   // ra 0..63
    const bf16* a0 = A + (long)ra * 1152 + ca;
    const bf16* b0 = B + (long)ra * 2304 + ca;
    const bf16* b1 = B + (long)(64 + ra) * 2304 + ca;
    const bf16* b2 = B + (long)(128 + ra) * 2304 + ca;
    const bf16* b3 = B + (long)(192 + ra) * 2304 + ca;
    char* lA = smem + wave * 1024;           // As buf stride 4096 B
    char* lB = smem + 8192 + wave * 1024;    // Bs buf stride 16384 B

    f32x4 acc[4][4] = {};
    // prologue: stage tile 0 into buf 0
    async_copy16(a0, lA);
    async_copy16(b0, lB);
    async_copy16(b1, lB + 4096);
    async_copy16(b2, lB + 8192);
    async_copy16(b3, lB + 12288);
    a0 += 32; b0 += 32; b1 += 32; b2 += 32; b3 += 32;
    int cur = 0;
#pragma unroll 1
    for (int k = 0; k < 36; ++k) {
        __syncthreads();
        if (k < 35) {
            char* nA = lA + ((cur ^ 1) << 12);
            char* nB = lB + ((cur ^ 1) << 14);
            async_copy16(a0, nA);
            async_copy16(b0, nB);
            async_copy16(b1, nB + 4096);
            async_copy16(b2, nB + 8192);
            async_copy16(b3, nB + 12288);
            a0 += 32; b0 += 32; b1 += 32; b2 += 32; b3 += 32;
        }
        const bf16* Ab = (const bf16*)(smem + cur * 4096);
        const bf16* Bb = (const bf16*)(smem + 8192 + cur * 16384);
        bf16x8 af[4], bfv[4];
#pragma unroll
        for (int t = 0; t < 4; ++t) {
            af[t]  = *(const bf16x8*)(Ab + (t * 16 + l16) * 32 + quad * 8);
            bfv[t] = *(const bf16x8*)(Bb + (wN + t * 16 + l16) * 32 + quad * 8);
        }
#pragma unroll
        for (int mt = 0; mt < 4; ++mt)
#pragma unroll
            for (int nt = 0; nt < 4; ++nt)
                acc[mt][nt] = __builtin_amdgcn_mfma_f32_16x16x32_bf16(
                    af[mt], bfv[nt], acc[mt][nt], 0, 0, 0);
        cur ^= 1;
    }

    // add m-dependent bias c[m]
    float cv[4];
#pragma unroll
    for (int nt = 0; nt < 4; ++nt) cv[nt] = cvec[b * 256 + wN + nt * 16 + l16];
#pragma unroll
    for (int mt = 0; mt < 4; ++mt)
#pragma unroll
        for (int nt = 0; nt < 4; ++nt)
#pragma unroll
            for (int r = 0; r < 4; ++r) acc[mt][nt][r] += cv[nt];

    const float scale = 0.029462782549439484f;  // 1/sqrt(1152)

    // PV B-tile stage: d-chunk ch (128 rows of VWT), k-slice kk (32 m), buffer buf.
    auto stageB = [&](int ch, int kk, int buf) {
        const bf16* src = VWTb + (long)(ch * 128 + wave * 32 + (lane >> 2)) * 256
                        + kk * 32 + (lane & 3) * 8;
        char* dst = smem + 34816 + buf * 8192 + wave * 2048;
        async_copy16(src, dst);
        async_copy16(src + 16 * 256, dst + 1024);
    };

    // softmax: row max across 4 waves via red
#pragma unroll
    for (int mt = 0; mt < 4; ++mt)
#pragma unroll
        for (int r = 0; r < 4; ++r) {
            float pm = fmaxf(fmaxf(acc[mt][0][r], acc[mt][1][r]),
                             fmaxf(acc[mt][2][r], acc[mt][3][r]));
#pragma unroll
            for (int off = 1; off <= 8; off <<= 1) pm = fmaxf(pm, __shfl_xor(pm, off));
            if (l16 == 0) red[(mt * 16 + quad * 4 + r) * 4 + wave] = pm;
        }
    __syncthreads();   // after this barrier all phase-1 As/Bs reads are done
    // issue first PV B-tile now: HBM latency hides under softmax tail + P-write
    stageB(0, 0, 0);
#pragma unroll
    for (int mt = 0; mt < 4; ++mt)
#pragma unroll
        for (int r = 0; r < 4; ++r) {
            const int R = mt * 16 + quad * 4 + r;
            float4 q = *(const float4*)(red + R * 4);
            float m = fmaxf(fmaxf(q.x, q.y), fmaxf(q.z, q.w));
            float ps = 0.0f;
#pragma unroll
            for (int nt = 0; nt < 4; ++nt) {
                float e = __expf((acc[mt][nt][r] - m) * scale);
                acc[mt][nt][r] = e;
                ps += e;
            }
#pragma unroll
            for (int off = 1; off <= 8; off <<= 1) ps += __shfl_xor(ps, off);
            if (l16 == 0) red2[R * 4 + wave] = ps;
        }
    __syncthreads();
    // normalize and write P (bf16) to P_lds (row stride 544 B)
#pragma unroll
    for (int mt = 0; mt < 4; ++mt)
#pragma unroll
        for (int r = 0; r < 4; ++r) {
            const int R = mt * 16 + quad * 4 + r;
            float4 q = *(const float4*)(red2 + R * 4);
            float inv = 1.0f / (q.x + q.y + q.z + q.w);
#pragma unroll
            for (int nt = 0; nt < 4; ++nt) {
                const int col = wN + nt * 16 + l16;
                *(bf16*)(smem + R * 544 + col * 2) = (bf16)(acc[mt][nt][r] * inv);
            }
        }

    // Phase 3: out[64 x 1152] = P @ VWT^T + bo. Wave w owns rows 16w..16w+16.
    // 9 d-chunks of 128 cols; K = 256 = 8 k-iters of 32; B double-buffered.
    const char* pA = smem + (wave * 16 + l16) * 544;
#pragma unroll 1
    for (int ch = 0; ch < 9; ++ch) {
        f32x4 acc2[8];
#pragma unroll
        for (int nt = 0; nt < 8; ++nt) acc2[nt] = (f32x4){0.f, 0.f, 0.f, 0.f};
#pragma unroll
        for (int kk = 0; kk < 8; ++kk) {
            __syncthreads();   // staged tile (ch,kk) landed; prev buf reads done
            {
                int nx = ch * 8 + kk + 1;
                if (nx < 72) stageB(nx >> 3, nx & 7, nx & 1);
            }
            const char* pb = smem + 34816 + (kk & 1) * 8192;
            bf16x8 af = *(const bf16x8*)(pA + kk * 64 + quad * 16);
#pragma unroll
            for (int nt = 0; nt < 8; ++nt) {
                bf16x8 bv8 = *(const bf16x8*)(pb + (nt * 16 + l16) * 64 + quad * 16);
                acc2[nt] = __builtin_amdgcn_mfma_f32_16x16x32_bf16(af, bv8, acc2[nt], 0, 0, 0);
            }
        }
        const int d0 = ch * 128;
        const long orow = b * 1024 + (long)bx * 64 + wave * 16 + quad * 4;
#pragma unroll
        for (int nt = 0; nt < 8; ++nt) {
            const int col = d0 + nt * 16 + l16;
            const float bvv = bo[col];
#pragma unroll
            for (int r = 0; r < 4; ++r)
                out[(orow + r) * 1152 + col] = acc2[nt][r] + bvv;
        }
    }
}

// Weight prep: z=0 Wq->slot0 (T), z=1 Wk->slot2 (T), z=2 Wv->slot3 (T),
// z=3 Wo->slot1 (plain). All fp32->bf16.
__global__ void cvt_wT_k(const float* __restrict__ Wq, const float* __restrict__ Wk,
                         const float* __restrict__ Wv, const float* __restrict__ Wo,
                         bf16* __restrict__ dst) {
    const int z = blockIdx.z;
    const int r0 = blockIdx.y * 64, c0 = blockIdx.x * 64;
    const int tid = threadIdx.x;
    if (z == 3) {
        // plain copy Wo -> slot 1
        int row = tid >> 2;
        int col = (tid & 3) * 16;
        const float* s = Wo + (long)(r0 + row) * 1152 + c0 + col;
        bf16* d = dst + 1327104 + (long)(r0 + row) * 1152 + c0 + col;
#pragma unroll
        for (int j = 0; j < 4; ++j) {
            float4 v = ((const float4*)s)[j];
            bf16x4 o = {(bf16)v.x, (bf16)v.y, (bf16)v.z, (bf16)v.w};
            ((bf16x4*)d)[j] = o;
        }
        return;
    }
    __shared__ bf16 t[64][66];
    const float* src = z == 0 ? Wq : z == 1 ? Wk : Wv;
    bf16* d = dst + (long)(z == 0 ? 0 : z == 1 ? 2 : 3) * 1327104;
    {
        int row = tid >> 4;
        int col4 = (tid & 15) * 4;
#pragma unroll
        for (int p = 0; p < 4; ++p) {
            int r = row + p * 16;
            float4 v = *(const float4*)(src + (long)(r0 + r) * 1152 + c0 + col4);
            t[col4 + 0][r] = (bf16)v.x;
            t[col4 + 1][r] = (bf16)v.y;
            t[col4 + 2][r] = (bf16)v.z;
            t[col4 + 3][r] = (bf16)v.w;
        }
    }
    __syncthreads();
    {
        int orow = tid >> 2;
        int oc = (tid & 3) * 16;
        bf16x8 a, b2;
#pragma unroll
        for (int j = 0; j < 8; ++j) { a[j] = t[orow][oc + j]; b2[j] = t[orow][oc + 8 + j]; }
        bf16* o = d + (long)(c0 + orow) * 1152 + r0 + oc;
        *(bf16x8*)o = a;
        *(bf16x8*)(o + 8) = b2;
    }
}

// x fp32 [32768 x 1152] -> xb bf16 (scattered per-64-row block into d_out at
// block_k*294912B + 147456B) + xm bf16 (mean over 4-row windows)
__global__ void cvt_merge_x_k(const float* __restrict__ x, bf16* __restrict__ xb,
                              bf16* __restrict__ xm) {
    int i = blockIdx.x * 256 + threadIdx.x;  // 8192*288 exact
    int w = i / 288;
    int c4 = i - w * 288;
    const float4* p = (const float4*)(x + (long)w * 4608) + c4;
    float4 a = p[0], b = p[288], c = p[576], d = p[864];
    bf16x4 oa = {(bf16)a.x, (bf16)a.y, (bf16)a.z, (bf16)a.w};
    bf16x4 ob = {(bf16)b.x, (bf16)b.y, (bf16)b.z, (bf16)b.w};
    bf16x4 oc = {(bf16)c.x, (bf16)c.y, (bf16)c.z, (bf16)c.w};
    bf16x4 od = {(bf16)d.x, (bf16)d.y, (bf16)d.z, (bf16)d.w};
    // global row r = w*4+j; block k = w>>4; row-in-block = (w&15)*4+j
    bf16* base = xb + (long)(w >> 4) * 147456 + 73728
               + (long)((w & 15) * 4) * 1152 + c4 * 4;
    *(bf16x4*)(base)        = oa;
    *(bf16x4*)(base + 1152) = ob;
    *(bf16x4*)(base + 2304) = oc;
    *(bf16x4*)(base + 3456) = od;
    float4 s;
    s.x = (a.x + b.x + c.x + d.x) * 0.25f;
    s.y = (a.y + b.y + c.y + d.y) * 0.25f;
    s.z = (a.z + b.z + c.z + d.z) * 0.25f;
    s.w = (a.w + b.w + c.w + d.w) * 0.25f;
    bf16x4 o = {(bf16)s.x, (bf16)s.y, (bf16)s.z, (bf16)s.w};
    *(bf16x4*)(xm + (long)w * 1152 + c4 * 4) = o;
}

// Merged weight rowdots: z=0: vk=WkT·bq (+zero biasUV[row]); z=1: biasUV[1152+row]=Wo·bv
__global__ void rowdot2_k(const bf16* __restrict__ WkT, const bf16* __restrict__ Wo_b,
                          const float* __restrict__ bq, const float* __restrict__ bv,
                          float* __restrict__ vk, float* __restrict__ biasUV) {
    const int z = blockIdx.y;
    const bf16* M = z ? Wo_b : WkT;
    const float* v = z ? bv : bq;
    const int row = blockIdx.x * 4 + (threadIdx.x >> 6);
    const int lane = threadIdx.x & 63;
    const bf16* mr = M + (long)row * 1152;
    float acc = 0.0f;
#pragma unroll
    for (int j = 0; j < 18; ++j)
        acc += (float)mr[j * 64 + lane] * v[j * 64 + lane];
#pragma unroll
    for (int off = 32; off; off >>= 1) acc += __shfl_xor(acc, off, 64);
    if (lane == 0) {
        if (z) biasUV[1152 + row] = acc;
        else { vk[row] = acc; biasUV[row] = 0.0f; }
    }
}

// out[row] = dot(M[row,0:1152], v). One wave per row.
__global__ void rowdot_k(const bf16* __restrict__ M, const float* __restrict__ v,
                         float* __restrict__ out) {
    const int row = blockIdx.x * 4 + (threadIdx.x >> 6);
    const int lane = threadIdx.x & 63;
    const bf16* mr = M + (long)row * 1152;
    float acc = 0.0f;
#pragma unroll
    for (int j = 0; j < 18; ++j)
        acc += (float)mr[j * 64 + lane] * v[j * 64 + lane];
#pragma unroll
    for (int off = 32; off; off >>= 1) acc += __shfl_xor(acc, off, 64);
    if (lane == 0) out[row] = acc;
}

// VW part of UVW [b*256+m][2304]@+1152 -> VWT:[b][1152][256]
__global__ void transpose_vm_k(const bf16* __restrict__ UVW, bf16* __restrict__ VT) {
    __shared__ bf16 t[64][65];
    const int tid = threadIdx.x;
    const int b = blockIdx.z;
    const int d0 = blockIdx.x * 64, m0 = blockIdx.y * 64;
#pragma unroll
    for (int p = 0; p < 2; ++p) {
        int r = (tid >> 3) + p * 32;
        int c = (tid & 7) * 8;
        bf16x8 v = *(const bf16x8*)(UVW + (long)(b * 256 + m0 + r) * 2304 + 1152 + d0 + c);
#pragma unroll
        for (int j = 0; j < 8; ++j) t[c + j][r] = v[j];
    }
    __syncthreads();
#pragma unroll
    for (int p = 0; p < 2; ++p) {
        int r = (tid >> 3) + p * 32;
        int c = (tid & 7) * 8;
        bf16x8 o;
#pragma unroll
        for (int j = 0; j < 8; ++j) o[j] = t[r][c + j];
        *(bf16x8*)(VT + (long)b * 294912 + (long)(d0 + r) * 256 + m0 + c) = o;
    }
}

extern "C" void kernel_launch(void* const* d_in, const int* in_sizes, int n_in,
                              void* d_out, int out_size, void* d_ws, size_t ws_size,
                              hipStream_t stream) {
    const float* x  = (const float*)d_in[0];
    const float* Wq = (const float*)d_in[1];
    const float* bq = (const float*)d_in[2];
    const float* Wk = (const float*)d_in[3];
    const float* bk = (const float*)d_in[4];  (void)bk;  // softmax-invariant
    const float* Wv = (const float*)d_in[5];
    const float* bv = (const float*)d_in[6];
    const float* Wo = (const float*)d_in[7];
    const float* bo = (const float*)d_in[8];
    float* out = (float*)d_out;
    char* ws = (char*)d_ws;

    // ws layout (~91 MB)
    bf16* WT4    = (bf16*)(ws);                  // [WqT | Wo | WkT | WvT], 10,616,832 B
    bf16* WkT_b  = WT4 + 2 * 1327104;
    bf16* Wo_b   = WT4 + 1 * 1327104;
    bf16* WQK2   = (bf16*)(ws + 10616832);       // [Wqk ; Wvo] [2304x1152], 5,308,416 B
    float* biasUV = (float*)(ws + 15925248);     // [2304] = [0 | Wo·bv]
    float* vk     = (float*)(ws + 15934464);     // [1152] = Wk^T·bq
    float* cvec   = (float*)(ws + 15939072);     // [8192] = x_m·vk
    bf16* xm_b   = (bf16*)(ws + 15971840);       // [8192x1152], 18,874,368 B
    bf16* UVW    = (bf16*)(ws + 34846208);       // [8192x2304], 37,748,736 B
    bf16* VWT    = (bf16*)(ws + 72594944);       // [32][1152][256], 18,874,368 B

    // d_out (151 MB fp32) doubles as x_b scratch: block k's x-tile (64 rows bf16,
    // 147456 B) lives in the SECOND half of block k's out region (294912 B). The
    // fused attn kernel reads its own x-tile (phase 1) before writing its out
    // region (phase 3) -> no cross-block aliasing regardless of dispatch order.
    bf16* x_b = (bf16*)d_out;

    // 1. weight prep: WqT, WkT, WvT (transposed) + Wo (plain), all bf16
    cvt_wT_k<<<dim3(18, 18, 4), 256, 0, stream>>>(Wq, Wk, Wv, Wo, WT4);
    cvt_merge_x_k<<<9216, 256, 0, stream>>>(x, x_b, xm_b);

    // 2. small vectors: vk = WkT·bq (+zero biasUV[0:1152]); biasUV[1152:] = Wo·bv
    rowdot2_k<<<dim3(288, 2), 256, 0, stream>>>(WkT_b, Wo_b, bq, bv, vk, biasUV);

    // 3. c[m] = x_m · vk
    rowdot_k<<<2048, 256, 0, stream>>>(xm_b, vk, cvec);

    // 4. Wqk = WqT·WkT^T = Wq^T·Wk (z=0); Wvo = Wo·WvT^T = Wo·Wv (z=1)
    gemm_bt<bf16, false><<<dim3(9, 9, 2), 256, 0, stream>>>(
        WT4, WT4 + 2 * 1327104, nullptr, WQK2,
        1152, 1152, 1152, 1152, 1152, 1.0f, 1327104, 1327104, 1327104);

    // 5. [U | VW] = x_m @ WQK2^T + biasUV
    gemm_bt<bf16, true><<<dim3(18, 64, 1), 256, 0, stream>>>(
        xm_b, WQK2, biasUV, UVW, 2304, 1152, 1152, 1152, 2304, 1.0f, 0, 0, 0);

    // 6. VWT = transpose(VW) per batch
    transpose_vm_k<<<dim3(18, 4, 32), 256, 0, stream>>>(UVW, VWT);

    // 7+8 fused: P = softmax((x@U^T + c)/sqrt(D)); out = P@VWT^T + bo
    attn_k<<<dim3(16, 32), 256, 0, stream>>>(x_b, UVW, VWT, cvec, bo, out);
}